// Round 19
// baseline (162.727 us; speedup 1.0000x reference)
//
#include <hip/hip_runtime.h>
#include <cstdint>
#include <cstddef>

#define B_ 64
#define N_ 16384
#define C_ 10
#define D_ 8
#define E_ 16
#define NTB_ 4                    // n per chunk (one K-quad)
#define NCHK_ 2                   // chunks per block  (r19: 4 -> 2)
#define NPB_ (NTB_ * NCHK_)       // 8 n per block
#define GRID_ (N_ / NPB_)         // 2048 blocks
#define SVOL_ (B_ * C_ * E_)      // 10240 floats
#define SVU_ (SVOL_ / 2)          // 5120 u32 (bf16 pairs)
#define WNU_ 640                  // u32 per n in Wb / wbuf
#define NJ_ 16                    // second-level partial count (r19: 32 -> 16)

typedef __attribute__((ext_vector_type(8))) short short8;
typedef __attribute__((ext_vector_type(2))) float f32x2;
typedef __attribute__((ext_vector_type(4))) float f32x4;
typedef __attribute__((ext_vector_type(2))) uint32_t u32x2;
typedef __attribute__((ext_vector_type(4))) uint32_t u32x4;

// single-instruction f32 pair -> packed bf16 (RNE), lo in [15:0]
__device__ __forceinline__ uint32_t pack2(float lo, float hi) {
  uint32_t r;
  asm("v_cvt_pk_bf16_f32 %0, %1, %2" : "=v"(r) : "v"(lo), "v"(hi));
  return r;
}
__device__ __forceinline__ float bflo(uint32_t w) {
  return __builtin_bit_cast(float, w << 16);
}
__device__ __forceinline__ float bfhi(uint32_t w) {
  return __builtin_bit_cast(float, w & 0xffff0000u);
}

// async global->LDS, 16 B per lane; g per-lane, l wave-uniform
__device__ __forceinline__ void gload16(const uint32_t* g, uint32_t* l) {
  __builtin_amdgcn_global_load_lds(
      (const __attribute__((address_space(1))) uint32_t*)g,
      (__attribute__((address_space(3))) uint32_t*)l, 16, 0, 0);
}

// ---------------------------------------------------------------------------
// Pass 0 (fused convert + uniform-c pass) — r15/r18-verified body, loop
// constants re-derived for NPB_=8 (x-stage: 4 its, q=gidx&15; xc write: 2 its).
// ---------------------------------------------------------------------------
template <int WB, int FLUSH>
__global__ __launch_bounds__(256) void pass0_kernel(
    const float* __restrict__ x, const float* __restrict__ W,
    uint32_t* __restrict__ Wb, uint32_t* __restrict__ xc,
    uint32_t* __restrict__ parts, float* __restrict__ souta, int ncopy)
{
  __shared__ __align__(16) uint32_t wbuf[2][NTB_ * WNU_];  // 2 x 10 KB
  __shared__ __align__(16) uint32_t xbuf[NPB_ * B_ * 4];   // 8 KB

  const int tid = threadIdx.x;
  const int lane = tid & 63;
  const int wv = tid >> 6;
  const int l15 = lane & 15;
  const int kg = lane >> 4;
  const int n0 = blockIdx.x * NPB_;
  const int b = wv * 16 + l15;

  f32x4 acc[C_];
#pragma unroll
  for (int c = 0; c < C_; ++c) acc[c] = (f32x4){0.f, 0.f, 0.f, 0.f};

  // stage x (f32 -> packed bf16), r8-verified pattern + XOR swizzle; NPB_=8:
  // 1024 f32x4 items, per b: 16 chunks (8n x 2dh)
#pragma unroll
  for (int it = 0; it < 4; ++it) {
    int gidx = it * 256 + tid;
    int bb = gidx >> 4, q = gidx & 15, nn2 = q >> 1, dh = q & 1;
    f32x4 v4 = *(const f32x4*)(x + (size_t)bb * (N_ * D_) +
                               (size_t)(n0 + nn2) * D_ + dh * 4);
    int base = (((nn2 * B_ + bb) * 4) ^ ((nn2 & 7) << 2)) + dh * 2;
    xbuf[base] = pack2(v4[0], v4[1]);
    xbuf[base + 1] = pack2(v4[2], v4[3]);
  }

  auto stage_w = [&](int pb, int nbase) {   // r8/r11-verified decode
#pragma unroll
    for (int it = 0; it < 10; ++it) {
      int i = it * 256 + tid;
      int n = i / 640, r = i - n * 640;
      int c = r >> 6, r2 = r & 63;
      int d2 = r2 >> 4, e = r2 & 15;
      const float* p = W + ((size_t)(nbase + n) * C_ + c) * 128 + d2 * 32 + e;
      wbuf[pb][n * WNU_ + (c * E_ + e) * 4 + d2] = pack2(p[0], p[16]);
    }
  };

  stage_w(0, n0);
  __syncthreads();

  if (WB) {  // coalesced xc side-write, DE-SWIZZLED so xc is linear
#pragma unroll
    for (int it = 0; it < 2; ++it) {
      int idx = it * 1024 + tid * 4;                 // linear xc offset
      int src = idx ^ (((idx >> 8) & 7) << 2);       // swizzled xbuf slot
      *(u32x4*)(xc + (size_t)n0 * 256 + idx) = *(const u32x4*)(xbuf + src);
    }
  }

  for (int ch = 0; ch < NCHK_; ++ch) {
    if (ch + 1 < NCHK_) stage_w((ch + 1) & 1, n0 + (ch + 1) * NTB_);
    const uint32_t* wb = wbuf[ch & 1];
    const int nl = ch * NTB_ + kg;
    short8 xq = *(const short8*)&xbuf[((nl * B_ + b) * 4) ^ ((nl & 7) << 2)];
#pragma unroll
    for (int c = 0; c < C_; ++c) {
      short8 wfq = *(const short8*)&wb[kg * WNU_ + (c * E_ + l15) * 4];
      acc[c] = __builtin_amdgcn_mfma_f32_16x16x32_bf16(wfq, xq, acc[c], 0, 0, 0);
    }
    if (WB) {  // coalesced Wb side-write of the chunk being consumed (linear)
      const size_t wdst = (size_t)(n0 + ch * NTB_) * WNU_;
#pragma unroll
      for (int it = 0; it < 10; ++it)
        Wb[wdst + it * 256 + tid] = wb[it * 256 + tid];
    }
    __syncthreads();
  }

  if (FLUSH == 1) {
    uint32_t* pc = parts + (size_t)blockIdx.x * SVU_;
#pragma unroll
    for (int c = 0; c < C_; ++c) {
      u32x2 w;
      w[0] = pack2(acc[c][0] * 0.1f, acc[c][1] * 0.1f);
      w[1] = pack2(acc[c][2] * 0.1f, acc[c][3] * 0.1f);
      *(u32x2*)&pc[(b * C_ + c) * 8 + kg * 2] = w;
    }
  } else {
    float* sc = souta + (size_t)(blockIdx.x & (ncopy - 1)) * SVOL_;
#pragma unroll
    for (int c = 0; c < C_; ++c)
#pragma unroll
      for (int r = 0; r < 4; ++r)
        atomicAdd(&sc[(b * C_ + c) * E_ + kg * 4 + r], acc[c][r] * 0.1f);
  }
}

// ---------------------------------------------------------------------------
// Routing passes 1/2 — r16/r18-verified body (gload_lds W staging + direct
// xc frag reads), NCHK_=2.  PRE=0 fallback: f32 staging (constants NPB_=8).
// ---------------------------------------------------------------------------
template <int PRE, int FLUSH>
__global__ __launch_bounds__(256) void accum_kernel(
    const float* __restrict__ x, const float* __restrict__ W,
    const uint32_t* __restrict__ Wb, const uint32_t* __restrict__ xc,
    const float* __restrict__ vacc, uint32_t* __restrict__ parts,
    float* __restrict__ souta, int ncopy)
{
  __shared__ __align__(16) uint32_t wbuf[2][NTB_ * WNU_];     // 2 x 10 KB
  __shared__ __align__(16) uint32_t xbuf[PRE ? 4 : NPB_ * B_ * 4];

  const int tid = threadIdx.x;
  const int lane = tid & 63;
  const int wv = tid >> 6;
  const int l15 = lane & 15;
  const int kg = lane >> 4;
  const int n0 = blockIdx.x * NPB_;
  const int b = wv * 16 + l15;

  const short8 kzero = (short8){0, 0, 0, 0, 0, 0, 0, 0};
  const f32x4 fzero = (f32x4){0.f, 0.f, 0.f, 0.f};

  f32x4 vf[C_];
#pragma unroll
  for (int c = 0; c < C_; ++c)
    vf[c] = *(const f32x4*)&vacc[(b * C_ + c) * E_ + kg * 4];

  f32x4 acc[C_];
#pragma unroll
  for (int c = 0; c < C_; ++c) acc[c] = fzero;

  // ---- stage x (PRE=0 fallback only; PRE=1 reads xc directly per chunk) ----
  if (!PRE) {
#pragma unroll
    for (int it = 0; it < 4; ++it) {
      int gidx = it * 256 + tid;
      int bb = gidx >> 4, q = gidx & 15, nn2 = q >> 1, dh = q & 1;
      f32x4 v4 = *(const f32x4*)(x + (size_t)bb * (N_ * D_) +
                                 (size_t)(n0 + nn2) * D_ + dh * 4);
      int base = (nn2 * B_ + bb) * 4 + dh * 2;
      xbuf[base] = pack2(v4[0], v4[1]);
      xbuf[base + 1] = pack2(v4[2], v4[3]);
    }
  }

  auto stage_w = [&](int pb, int nbase) {
    if (PRE) {
      const uint32_t* src = Wb + (size_t)nbase * WNU_;
#pragma unroll
      for (int k = 0; k < 3; ++k) {
        int u = wv + 4 * k;
        if (u < 10) gload16(src + u * 256 + lane * 4, &wbuf[pb][u * 256]);
      }
    } else {
#pragma unroll
      for (int it = 0; it < 10; ++it) {
        int i = it * 256 + tid;
        int n = i / 640, r = i - n * 640;
        int c = r >> 6, r2 = r & 63;
        int d2 = r2 >> 4, e = r2 & 15;
        const float* p = W + ((size_t)(nbase + n) * C_ + c) * 128 + d2 * 32 + e;
        wbuf[pb][n * WNU_ + (c * E_ + e) * 4 + d2] = pack2(p[0], p[16]);
      }
    }
  };

  stage_w(0, n0);
  __syncthreads();

  for (int ch = 0; ch < NCHK_; ++ch) {
    if (ch + 1 < NCHK_) stage_w((ch + 1) & 1, n0 + (ch + 1) * NTB_);
    const uint32_t* wb = wbuf[ch & 1];

    const int nl = ch * NTB_ + kg;
    short8 xq;
    if (PRE) {
      // r16-verified: direct xc read (identity with the old xbuf copy)
      xq = *(const short8*)&xc[((size_t)(n0 + nl) * B_ + b) * 4];
    } else {
      xq = *(const short8*)&xbuf[(nl * B_ + b) * 4];
    }

    short8 xm0 = (kg == 0) ? xq : kzero;
    short8 xm1 = (kg == 1) ? xq : kzero;
    short8 xm2 = (kg == 2) ? xq : kzero;
    short8 xm3 = (kg == 3) ? xq : kzero;
    const bool bb0 = (kg & 1) != 0;
    const bool bb1 = (kg & 2) != 0;

    // ---- Phase L (r9-verified): logits + softmax, 1 exp per c ----
    float ew[C_];
#pragma unroll
    for (int c = 0; c < C_; ++c) {
      short8 wfq = *(const short8*)&wb[kg * WNU_ + (c * E_ + l15) * 4];
      f32x4 u0 = __builtin_amdgcn_mfma_f32_16x16x32_bf16(wfq, xm0, fzero, 0, 0, 0);
      f32x4 u1 = __builtin_amdgcn_mfma_f32_16x16x32_bf16(wfq, xm1, fzero, 0, 0, 0);
      f32x4 u2 = __builtin_amdgcn_mfma_f32_16x16x32_bf16(wfq, xm2, fzero, 0, 0, 0);
      f32x4 u3 = __builtin_amdgcn_mfma_f32_16x16x32_bf16(wfq, xm3, fzero, 0, 0, 0);
      f32x4 v = vf[c];
      float t0 = u0[0] * v[0] + u0[1] * v[1] + u0[2] * v[2] + u0[3] * v[3];
      float t1 = u1[0] * v[0] + u1[1] * v[1] + u1[2] * v[2] + u1[3] * v[3];
      float t2 = u2[0] * v[0] + u2[1] * v[1] + u2[2] * v[2] + u2[3] * v[3];
      float t3 = u3[0] * v[0] + u3[1] * v[1] + u3[2] * v[2] + u3[3] * v[3];
      float keep_lo = bb0 ? t1 : t0, send_lo = bb0 ? t0 : t1;
      float keep_hi = bb0 ? t3 : t2, send_hi = bb0 ? t2 : t3;
      float ulo = keep_lo + __shfl_xor(send_lo, 16);
      float uhi = keep_hi + __shfl_xor(send_hi, 16);
      float keep2 = bb1 ? uhi : ulo, send2 = bb1 ? ulo : uhi;
      float logit = keep2 + __shfl_xor(send2, 32);
      ew[c] = __expf(logit);
    }
    float s01 = ew[0] + ew[1], s23 = ew[2] + ew[3], s45 = ew[4] + ew[5],
          s67 = ew[6] + ew[7], s89 = ew[8] + ew[9];
    float inv = __builtin_amdgcn_rcpf(((s01 + s23) + (s45 + s67)) + s89);

    // ---- Phase S (r7/r9-verified): bf16(cw*x) B, full-K MFMA ----
    float xf[D_];
#pragma unroll
    for (int j = 0; j < D_; ++j) {
      uint32_t hw = (uint32_t)(uint16_t)xq[j];
      xf[j] = __builtin_bit_cast(float, hw << 16);
    }
#pragma unroll
    for (int c = 0; c < C_; ++c) {
      float cw = ew[c] * inv;
      u32x4 bw;
      bw[0] = pack2(cw * xf[0], cw * xf[1]);
      bw[1] = pack2(cw * xf[2], cw * xf[3]);
      bw[2] = pack2(cw * xf[4], cw * xf[5]);
      bw[3] = pack2(cw * xf[6], cw * xf[7]);
      short8 bfrag = __builtin_bit_cast(short8, bw);
      short8 wfq = *(const short8*)&wb[kg * WNU_ + (c * E_ + l15) * 4];
      acc[c] = __builtin_amdgcn_mfma_f32_16x16x32_bf16(wfq, bfrag, acc[c], 0, 0, 0);
    }
    __syncthreads();
  }

  if (FLUSH == 1) {
    uint32_t* pc = parts + (size_t)blockIdx.x * SVU_;
#pragma unroll
    for (int c = 0; c < C_; ++c) {
      u32x2 w;
      w[0] = pack2(acc[c][0], acc[c][1]);
      w[1] = pack2(acc[c][2], acc[c][3]);
      *(u32x2*)&pc[(b * C_ + c) * 8 + kg * 2] = w;
    }
  } else {
    float* sc = souta + (size_t)(blockIdx.x & (ncopy - 1)) * SVOL_;
#pragma unroll
    for (int c = 0; c < C_; ++c)
#pragma unroll
      for (int r = 0; r < 4; ++r)
        atomicAdd(&sc[(b * C_ + c) * E_ + kg * 4 + r], acc[c][r]);
  }
}

// ---------------------------------------------------------------------------
// Fold 2048 bf16 block-partials -> 16 f32 partials (r11-verified pattern).
// ---------------------------------------------------------------------------
__global__ __launch_bounds__(256) void reduce32_kernel(
    const uint32_t* __restrict__ parts, float* __restrict__ out32)
{
  int j = blockIdx.x / (SVU_ / 256);     // 0..NJ_-1
  int seg = blockIdx.x % (SVU_ / 256);   // 0..19
  int t = seg * 256 + threadIdx.x;       // 0..5119
  float s0 = 0.f, s1 = 0.f;
#pragma unroll 4
  for (int k = j * (GRID_ / NJ_); k < (j + 1) * (GRID_ / NJ_); ++k) {
    uint32_t w = parts[(size_t)k * SVU_ + t];
    s0 += bflo(w);
    s1 += bfhi(w);
  }
  *(f32x2*)&out32[(size_t)j * SVOL_ + t * 2] = (f32x2){s0, s1};
}

// ---------------------------------------------------------------------------
// Reduce np f32 partials, apply squash (r9-verified).
// MODE 0: vacc = v   MODE 1: vacc += v   MODE 2: out = v
// ---------------------------------------------------------------------------
template <int MODE>
__global__ __launch_bounds__(256) void squash_kernel(
    const float* __restrict__ scopy, int np,
    float* __restrict__ vacc, float* __restrict__ out)
{
  int t = blockIdx.x * 256 + threadIdx.x;  // 0..10239
  float sv = 0.f;
#pragma unroll 8
  for (int k = 0; k < np; ++k) sv += scopy[(size_t)k * SVOL_ + t];
  float sq = sv * sv;
  sq += __shfl_xor(sq, 1);
  sq += __shfl_xor(sq, 2);
  sq += __shfl_xor(sq, 4);
  sq += __shfl_xor(sq, 8);
  float scale = sq / (1.f + sq) * rsqrtf(sq + 1e-7f);
  float v = scale * sv;
  if (MODE == 0)      vacc[t] = v;
  else if (MODE == 1) vacc[t] += v;
  else                out[t] = v;
}

// legacy striped-squash for the atomic fallback tier (r7-verified)
template <int MODE>
__global__ __launch_bounds__(256) void squash_stripes_kernel(
    float* __restrict__ scopy, int ncopy,
    float* __restrict__ vacc, float* __restrict__ out)
{
  int t = blockIdx.x * 256 + threadIdx.x;
  float sv = 0.f;
  for (int k = 0; k < ncopy; ++k) {
    sv += scopy[(size_t)k * SVOL_ + t];
    if (MODE != 2) scopy[(size_t)k * SVOL_ + t] = 0.f;
  }
  float sq = sv * sv;
  sq += __shfl_xor(sq, 1);
  sq += __shfl_xor(sq, 2);
  sq += __shfl_xor(sq, 4);
  sq += __shfl_xor(sq, 8);
  float scale = sq / (1.f + sq) * rsqrtf(sq + 1e-7f);
  float v = scale * sv;
  if (MODE == 0)      vacc[t] = v;
  else if (MODE == 1) vacc[t] += v;
  else                out[t] = v;
}

extern "C" void kernel_launch(void* const* d_in, const int* in_sizes, int n_in,
                              void* d_out, int out_size, void* d_ws, size_t ws_size,
                              hipStream_t stream)
{
  const float* x = (const float*)d_in[0];  // [64][16384][8]
  const float* W = (const float*)d_in[1];  // [16384][10][8][16]
  float* out = (float*)d_out;              // [64][10][16]

  const size_t WB_SZ = (size_t)N_ * WNU_ * 4;            // 41.9 MB
  const size_t XC_SZ = (size_t)N_ * B_ * 4 * 4;          // 16.8 MB
  const size_t PARTS_SZ = (size_t)GRID_ * SVU_ * 4;      // 41.9 MB
  const size_t OUT32_SZ = (size_t)NJ_ * SVOL_ * 4;       // 0.66 MB
  const size_t VACC_SZ = (size_t)SVOL_ * 4;
  const int RB = NJ_ * (SVU_ / 256);                     // 320
  const int SB = SVOL_ / 256;                            // 40

  if (ws_size >= WB_SZ + XC_SZ + PARTS_SZ + OUT32_SZ + VACC_SZ) {
    // ---- tier A: fused convert in pass0, bf16 partials ----
    uint32_t* Wb = (uint32_t*)d_ws;
    uint32_t* xcv = (uint32_t*)((char*)d_ws + WB_SZ);
    uint32_t* parts = (uint32_t*)((char*)d_ws + WB_SZ + XC_SZ);
    float* out32 = (float*)((char*)d_ws + WB_SZ + XC_SZ + PARTS_SZ);
    float* vacc = out32 + (size_t)NJ_ * SVOL_;

    pass0_kernel<1, 1><<<GRID_, 256, 0, stream>>>(x, W, Wb, xcv, parts, nullptr, 0);
    reduce32_kernel<<<RB, 256, 0, stream>>>(parts, out32);
    squash_kernel<0><<<SB, 256, 0, stream>>>(out32, NJ_, vacc, out);

    accum_kernel<1, 1><<<GRID_, 256, 0, stream>>>(x, W, Wb, xcv, vacc, parts, nullptr, 0);
    reduce32_kernel<<<RB, 256, 0, stream>>>(parts, out32);
    squash_kernel<1><<<SB, 256, 0, stream>>>(out32, NJ_, vacc, out);

    accum_kernel<1, 1><<<GRID_, 256, 0, stream>>>(x, W, Wb, xcv, vacc, parts, nullptr, 0);
    reduce32_kernel<<<RB, 256, 0, stream>>>(parts, out32);
    squash_kernel<2><<<SB, 256, 0, stream>>>(out32, NJ_, vacc, out);
  } else if (ws_size >= PARTS_SZ + OUT32_SZ + VACC_SZ) {
    // ---- tier B: no room for Wb/xc; f32 staging each pass ----
    uint32_t* parts = (uint32_t*)d_ws;
    float* out32 = (float*)((char*)d_ws + PARTS_SZ);
    float* vacc = out32 + (size_t)NJ_ * SVOL_;

    pass0_kernel<0, 1><<<GRID_, 256, 0, stream>>>(x, W, nullptr, nullptr, parts, nullptr, 0);
    reduce32_kernel<<<RB, 256, 0, stream>>>(parts, out32);
    squash_kernel<0><<<SB, 256, 0, stream>>>(out32, NJ_, vacc, out);

    accum_kernel<0, 1><<<GRID_, 256, 0, stream>>>(x, W, nullptr, nullptr, vacc, parts, nullptr, 0);
    reduce32_kernel<<<RB, 256, 0, stream>>>(parts, out32);
    squash_kernel<1><<<SB, 256, 0, stream>>>(out32, NJ_, vacc, out);

    accum_kernel<0, 1><<<GRID_, 256, 0, stream>>>(x, W, nullptr, nullptr, vacc, parts, nullptr, 0);
    reduce32_kernel<<<RB, 256, 0, stream>>>(parts, out32);
    squash_kernel<2><<<SB, 256, 0, stream>>>(out32, NJ_, vacc, out);
  } else {
    // ---- tier C: atomic stripes (r7-verified) ----
    int ncopy = 64;
    while (ncopy > 1 && (size_t)(ncopy + 1) * SVOL_ * 4 > ws_size) ncopy >>= 1;
    float* s_ws = (float*)d_ws;
    float* vacc = s_ws + (size_t)ncopy * SVOL_;
    hipMemsetAsync(s_ws, 0, (size_t)ncopy * SVOL_ * 4, stream);

    pass0_kernel<0, 0><<<GRID_, 256, 0, stream>>>(x, W, nullptr, nullptr, nullptr, s_ws, ncopy);
    squash_stripes_kernel<0><<<SB, 256, 0, stream>>>(s_ws, ncopy, vacc, out);

    accum_kernel<0, 0><<<GRID_, 256, 0, stream>>>(x, W, nullptr, nullptr, vacc, nullptr, s_ws, ncopy);
    squash_stripes_kernel<1><<<SB, 256, 0, stream>>>(s_ws, ncopy, vacc, out);

    accum_kernel<0, 0><<<GRID_, 256, 0, stream>>>(x, W, nullptr, nullptr, vacc, nullptr, s_ws, ncopy);
    squash_stripes_kernel<2><<<SB, 256, 0, stream>>>(s_ws, ncopy, vacc, out);
  }
}

// Round 20
// 131.162 us; speedup vs baseline: 1.2407x; 1.2407x over previous
//
#include <hip/hip_runtime.h>
#include <cstdint>
#include <cstddef>

#define B_ 64
#define N_ 16384
#define C_ 10
#define D_ 8
#define E_ 16
#define NTB_ 4                    // n per chunk (one K-quad)
#define NCHK_ 4                   // chunks per block
#define NPB_ (NTB_ * NCHK_)       // 16 n per block
#define GRID_ (N_ / NPB_)         // 1024 blocks
#define SVOL_ (B_ * C_ * E_)      // 10240 floats
#define SVU_ (SVOL_ / 2)          // 5120 u32 (bf16 pairs)
#define WNU_ 640                  // u32 per n in Wb / wbuf
#define NJ_ 32                    // second-level partial count

typedef __attribute__((ext_vector_type(8))) short short8;
typedef __attribute__((ext_vector_type(2))) float f32x2;
typedef __attribute__((ext_vector_type(4))) float f32x4;
typedef __attribute__((ext_vector_type(2))) uint32_t u32x2;
typedef __attribute__((ext_vector_type(4))) uint32_t u32x4;

// single-instruction f32 pair -> packed bf16 (RNE), lo in [15:0]
__device__ __forceinline__ uint32_t pack2(float lo, float hi) {
  uint32_t r;
  asm("v_cvt_pk_bf16_f32 %0, %1, %2" : "=v"(r) : "v"(lo), "v"(hi));
  return r;
}
__device__ __forceinline__ float bflo(uint32_t w) {
  return __builtin_bit_cast(float, w << 16);
}
__device__ __forceinline__ float bfhi(uint32_t w) {
  return __builtin_bit_cast(float, w & 0xffff0000u);
}

// async global->LDS, 16 B per lane; g per-lane, l wave-uniform
__device__ __forceinline__ void gload16(const uint32_t* g, uint32_t* l) {
  __builtin_amdgcn_global_load_lds(
      (const __attribute__((address_space(1))) uint32_t*)g,
      (__attribute__((address_space(3))) uint32_t*)l, 16, 0, 0);
}

// ---------------------------------------------------------------------------
// Pass 0 (fused convert + uniform-c pass) — r18-verified build (131.49 us):
// r8 XOR-swizzled x staging, linear xc/Wb side-writes, K-quad full-K MFMA,
// bf16 parts flush, __launch_bounds__(256) (no min-waves pin).
// ---------------------------------------------------------------------------
template <int WB, int FLUSH>
__global__ __launch_bounds__(256) void pass0_kernel(
    const float* __restrict__ x, const float* __restrict__ W,
    uint32_t* __restrict__ Wb, uint32_t* __restrict__ xc,
    uint32_t* __restrict__ parts, float* __restrict__ souta, int ncopy)
{
  __shared__ __align__(16) uint32_t wbuf[2][NTB_ * WNU_];  // 2 x 10 KB
  __shared__ __align__(16) uint32_t xbuf[NPB_ * B_ * 4];   // 16 KB

  const int tid = threadIdx.x;
  const int lane = tid & 63;
  const int wv = tid >> 6;
  const int l15 = lane & 15;
  const int kg = lane >> 4;
  const int n0 = blockIdx.x * NPB_;
  const int b = wv * 16 + l15;

  f32x4 acc[C_];
#pragma unroll
  for (int c = 0; c < C_; ++c) acc[c] = (f32x4){0.f, 0.f, 0.f, 0.f};

  // stage x (f32 -> packed bf16), r8-verified pattern WITH r8's XOR swizzle
#pragma unroll
  for (int it = 0; it < 8; ++it) {
    int gidx = it * 256 + tid;
    int bb = gidx >> 5, q = gidx & 31, nn2 = q >> 1, dh = q & 1;
    f32x4 v4 = *(const f32x4*)(x + (size_t)bb * (N_ * D_) +
                               (size_t)(n0 + nn2) * D_ + dh * 4);
    int base = (((nn2 * B_ + bb) * 4) ^ ((nn2 & 7) << 2)) + dh * 2;
    xbuf[base] = pack2(v4[0], v4[1]);
    xbuf[base + 1] = pack2(v4[2], v4[3]);
  }

  auto stage_w = [&](int pb, int nbase) {   // r8/r11-verified decode
#pragma unroll
    for (int it = 0; it < 10; ++it) {
      int i = it * 256 + tid;
      int n = i / 640, r = i - n * 640;
      int c = r >> 6, r2 = r & 63;
      int d2 = r2 >> 4, e = r2 & 15;
      const float* p = W + ((size_t)(nbase + n) * C_ + c) * 128 + d2 * 32 + e;
      wbuf[pb][n * WNU_ + (c * E_ + e) * 4 + d2] = pack2(p[0], p[16]);
    }
  };

  stage_w(0, n0);
  __syncthreads();

  if (WB) {  // coalesced xc side-write, DE-SWIZZLED so xc is linear
#pragma unroll
    for (int it = 0; it < 4; ++it) {
      int idx = it * 1024 + tid * 4;                 // linear xc offset
      int src = idx ^ (((idx >> 8) & 7) << 2);       // swizzled xbuf slot
      *(u32x4*)(xc + (size_t)n0 * 256 + idx) = *(const u32x4*)(xbuf + src);
    }
  }

  for (int ch = 0; ch < NCHK_; ++ch) {
    if (ch + 1 < NCHK_) stage_w((ch + 1) & 1, n0 + (ch + 1) * NTB_);
    const uint32_t* wb = wbuf[ch & 1];
    const int nl = ch * NTB_ + kg;
    short8 xq = *(const short8*)&xbuf[((nl * B_ + b) * 4) ^ ((nl & 7) << 2)];
#pragma unroll
    for (int c = 0; c < C_; ++c) {
      short8 wfq = *(const short8*)&wb[kg * WNU_ + (c * E_ + l15) * 4];
      acc[c] = __builtin_amdgcn_mfma_f32_16x16x32_bf16(wfq, xq, acc[c], 0, 0, 0);
    }
    if (WB) {  // coalesced Wb side-write of the chunk being consumed (linear)
      const size_t wdst = (size_t)(n0 + ch * NTB_) * WNU_;
#pragma unroll
      for (int it = 0; it < 10; ++it)
        Wb[wdst + it * 256 + tid] = wb[it * 256 + tid];
    }
    __syncthreads();
  }

  if (FLUSH == 1) {
    uint32_t* pc = parts + (size_t)blockIdx.x * SVU_;
#pragma unroll
    for (int c = 0; c < C_; ++c) {
      u32x2 w;
      w[0] = pack2(acc[c][0] * 0.1f, acc[c][1] * 0.1f);
      w[1] = pack2(acc[c][2] * 0.1f, acc[c][3] * 0.1f);
      *(u32x2*)&pc[(b * C_ + c) * 8 + kg * 2] = w;
    }
  } else {
    float* sc = souta + (size_t)(blockIdx.x & (ncopy - 1)) * SVOL_;
#pragma unroll
    for (int c = 0; c < C_; ++c)
#pragma unroll
      for (int r = 0; r < 4; ++r)
        atomicAdd(&sc[(b * C_ + c) * E_ + kg * 4 + r], acc[c][r] * 0.1f);
  }
}

// ---------------------------------------------------------------------------
// Routing passes 1/2 — r18-verified build. PRE=1: gload_lds W staging +
// direct xc frag reads; PRE=0 fallback: f32 staging.
// ---------------------------------------------------------------------------
template <int PRE, int FLUSH>
__global__ __launch_bounds__(256) void accum_kernel(
    const float* __restrict__ x, const float* __restrict__ W,
    const uint32_t* __restrict__ Wb, const uint32_t* __restrict__ xc,
    const float* __restrict__ vacc, uint32_t* __restrict__ parts,
    float* __restrict__ souta, int ncopy)
{
  __shared__ __align__(16) uint32_t wbuf[2][NTB_ * WNU_];     // 2 x 10 KB
  __shared__ __align__(16) uint32_t xbuf[PRE ? 4 : NPB_ * B_ * 4];

  const int tid = threadIdx.x;
  const int lane = tid & 63;
  const int wv = tid >> 6;
  const int l15 = lane & 15;
  const int kg = lane >> 4;
  const int n0 = blockIdx.x * NPB_;
  const int b = wv * 16 + l15;

  const short8 kzero = (short8){0, 0, 0, 0, 0, 0, 0, 0};
  const f32x4 fzero = (f32x4){0.f, 0.f, 0.f, 0.f};

  f32x4 vf[C_];
#pragma unroll
  for (int c = 0; c < C_; ++c)
    vf[c] = *(const f32x4*)&vacc[(b * C_ + c) * E_ + kg * 4];

  f32x4 acc[C_];
#pragma unroll
  for (int c = 0; c < C_; ++c) acc[c] = fzero;

  // ---- stage x (PRE=0 fallback only; PRE=1 reads xc directly per chunk) ----
  if (!PRE) {
#pragma unroll
    for (int it = 0; it < 8; ++it) {
      int gidx = it * 256 + tid;
      int bb = gidx >> 5, q = gidx & 31, nn2 = q >> 1, dh = q & 1;
      f32x4 v4 = *(const f32x4*)(x + (size_t)bb * (N_ * D_) +
                                 (size_t)(n0 + nn2) * D_ + dh * 4);
      int base = (nn2 * B_ + bb) * 4 + dh * 2;
      xbuf[base] = pack2(v4[0], v4[1]);
      xbuf[base + 1] = pack2(v4[2], v4[3]);
    }
  }

  auto stage_w = [&](int pb, int nbase) {
    if (PRE) {
      const uint32_t* src = Wb + (size_t)nbase * WNU_;
#pragma unroll
      for (int k = 0; k < 3; ++k) {
        int u = wv + 4 * k;
        if (u < 10) gload16(src + u * 256 + lane * 4, &wbuf[pb][u * 256]);
      }
    } else {
#pragma unroll
      for (int it = 0; it < 10; ++it) {
        int i = it * 256 + tid;
        int n = i / 640, r = i - n * 640;
        int c = r >> 6, r2 = r & 63;
        int d2 = r2 >> 4, e = r2 & 15;
        const float* p = W + ((size_t)(nbase + n) * C_ + c) * 128 + d2 * 32 + e;
        wbuf[pb][n * WNU_ + (c * E_ + e) * 4 + d2] = pack2(p[0], p[16]);
      }
    }
  };

  stage_w(0, n0);
  __syncthreads();

  for (int ch = 0; ch < NCHK_; ++ch) {
    if (ch + 1 < NCHK_) stage_w((ch + 1) & 1, n0 + (ch + 1) * NTB_);
    const uint32_t* wb = wbuf[ch & 1];

    const int nl = ch * NTB_ + kg;
    short8 xq;
    if (PRE) {
      // r16-verified: direct xc read (identity with the old xbuf copy)
      xq = *(const short8*)&xc[((size_t)(n0 + nl) * B_ + b) * 4];
    } else {
      xq = *(const short8*)&xbuf[(nl * B_ + b) * 4];
    }

    short8 xm0 = (kg == 0) ? xq : kzero;
    short8 xm1 = (kg == 1) ? xq : kzero;
    short8 xm2 = (kg == 2) ? xq : kzero;
    short8 xm3 = (kg == 3) ? xq : kzero;
    const bool bb0 = (kg & 1) != 0;
    const bool bb1 = (kg & 2) != 0;

    // ---- Phase L (r9-verified): logits + softmax, 1 exp per c ----
    float ew[C_];
#pragma unroll
    for (int c = 0; c < C_; ++c) {
      short8 wfq = *(const short8*)&wb[kg * WNU_ + (c * E_ + l15) * 4];
      f32x4 u0 = __builtin_amdgcn_mfma_f32_16x16x32_bf16(wfq, xm0, fzero, 0, 0, 0);
      f32x4 u1 = __builtin_amdgcn_mfma_f32_16x16x32_bf16(wfq, xm1, fzero, 0, 0, 0);
      f32x4 u2 = __builtin_amdgcn_mfma_f32_16x16x32_bf16(wfq, xm2, fzero, 0, 0, 0);
      f32x4 u3 = __builtin_amdgcn_mfma_f32_16x16x32_bf16(wfq, xm3, fzero, 0, 0, 0);
      f32x4 v = vf[c];
      float t0 = u0[0] * v[0] + u0[1] * v[1] + u0[2] * v[2] + u0[3] * v[3];
      float t1 = u1[0] * v[0] + u1[1] * v[1] + u1[2] * v[2] + u1[3] * v[3];
      float t2 = u2[0] * v[0] + u2[1] * v[1] + u2[2] * v[2] + u2[3] * v[3];
      float t3 = u3[0] * v[0] + u3[1] * v[1] + u3[2] * v[2] + u3[3] * v[3];
      float keep_lo = bb0 ? t1 : t0, send_lo = bb0 ? t0 : t1;
      float keep_hi = bb0 ? t3 : t2, send_hi = bb0 ? t2 : t3;
      float ulo = keep_lo + __shfl_xor(send_lo, 16);
      float uhi = keep_hi + __shfl_xor(send_hi, 16);
      float keep2 = bb1 ? uhi : ulo, send2 = bb1 ? ulo : uhi;
      float logit = keep2 + __shfl_xor(send2, 32);
      ew[c] = __expf(logit);
    }
    float s01 = ew[0] + ew[1], s23 = ew[2] + ew[3], s45 = ew[4] + ew[5],
          s67 = ew[6] + ew[7], s89 = ew[8] + ew[9];
    float inv = __builtin_amdgcn_rcpf(((s01 + s23) + (s45 + s67)) + s89);

    // ---- Phase S (r7/r9-verified): bf16(cw*x) B, full-K MFMA ----
    float xf[D_];
#pragma unroll
    for (int j = 0; j < D_; ++j) {
      uint32_t hw = (uint32_t)(uint16_t)xq[j];
      xf[j] = __builtin_bit_cast(float, hw << 16);
    }
#pragma unroll
    for (int c = 0; c < C_; ++c) {
      float cw = ew[c] * inv;
      u32x4 bw;
      bw[0] = pack2(cw * xf[0], cw * xf[1]);
      bw[1] = pack2(cw * xf[2], cw * xf[3]);
      bw[2] = pack2(cw * xf[4], cw * xf[5]);
      bw[3] = pack2(cw * xf[6], cw * xf[7]);
      short8 bfrag = __builtin_bit_cast(short8, bw);
      short8 wfq = *(const short8*)&wb[kg * WNU_ + (c * E_ + l15) * 4];
      acc[c] = __builtin_amdgcn_mfma_f32_16x16x32_bf16(wfq, bfrag, acc[c], 0, 0, 0);
    }
    __syncthreads();
  }

  if (FLUSH == 1) {
    uint32_t* pc = parts + (size_t)blockIdx.x * SVU_;
#pragma unroll
    for (int c = 0; c < C_; ++c) {
      u32x2 w;
      w[0] = pack2(acc[c][0], acc[c][1]);
      w[1] = pack2(acc[c][2], acc[c][3]);
      *(u32x2*)&pc[(b * C_ + c) * 8 + kg * 2] = w;
    }
  } else {
    float* sc = souta + (size_t)(blockIdx.x & (ncopy - 1)) * SVOL_;
#pragma unroll
    for (int c = 0; c < C_; ++c)
#pragma unroll
      for (int r = 0; r < 4; ++r)
        atomicAdd(&sc[(b * C_ + c) * E_ + kg * 4 + r], acc[c][r]);
  }
}

// ---------------------------------------------------------------------------
// Fold 1024 bf16 block-partials -> 32 f32 partials (r11-verified).
// ---------------------------------------------------------------------------
__global__ __launch_bounds__(256) void reduce32_kernel(
    const uint32_t* __restrict__ parts, float* __restrict__ out32)
{
  int j = blockIdx.x / (SVU_ / 256);     // 0..31
  int seg = blockIdx.x % (SVU_ / 256);   // 0..19
  int t = seg * 256 + threadIdx.x;       // 0..5119
  float s0 = 0.f, s1 = 0.f;
#pragma unroll 4
  for (int k = j * (GRID_ / NJ_); k < (j + 1) * (GRID_ / NJ_); ++k) {
    uint32_t w = parts[(size_t)k * SVU_ + t];
    s0 += bflo(w);
    s1 += bfhi(w);
  }
  *(f32x2*)&out32[(size_t)j * SVOL_ + t * 2] = (f32x2){s0, s1};
}

// ---------------------------------------------------------------------------
// Reduce np f32 partials, apply squash (r9-verified).
// MODE 0: vacc = v   MODE 1: vacc += v   MODE 2: out = v
// ---------------------------------------------------------------------------
template <int MODE>
__global__ __launch_bounds__(256) void squash_kernel(
    const float* __restrict__ scopy, int np,
    float* __restrict__ vacc, float* __restrict__ out)
{
  int t = blockIdx.x * 256 + threadIdx.x;  // 0..10239
  float sv = 0.f;
#pragma unroll 8
  for (int k = 0; k < np; ++k) sv += scopy[(size_t)k * SVOL_ + t];
  float sq = sv * sv;
  sq += __shfl_xor(sq, 1);
  sq += __shfl_xor(sq, 2);
  sq += __shfl_xor(sq, 4);
  sq += __shfl_xor(sq, 8);
  float scale = sq / (1.f + sq) * rsqrtf(sq + 1e-7f);
  float v = scale * sv;
  if (MODE == 0)      vacc[t] = v;
  else if (MODE == 1) vacc[t] += v;
  else                out[t] = v;
}

// legacy striped-squash for the atomic fallback tier (r7-verified)
template <int MODE>
__global__ __launch_bounds__(256) void squash_stripes_kernel(
    float* __restrict__ scopy, int ncopy,
    float* __restrict__ vacc, float* __restrict__ out)
{
  int t = blockIdx.x * 256 + threadIdx.x;
  float sv = 0.f;
  for (int k = 0; k < ncopy; ++k) {
    sv += scopy[(size_t)k * SVOL_ + t];
    if (MODE != 2) scopy[(size_t)k * SVOL_ + t] = 0.f;
  }
  float sq = sv * sv;
  sq += __shfl_xor(sq, 1);
  sq += __shfl_xor(sq, 2);
  sq += __shfl_xor(sq, 4);
  sq += __shfl_xor(sq, 8);
  float scale = sq / (1.f + sq) * rsqrtf(sq + 1e-7f);
  float v = scale * sv;
  if (MODE == 0)      vacc[t] = v;
  else if (MODE == 1) vacc[t] += v;
  else                out[t] = v;
}

extern "C" void kernel_launch(void* const* d_in, const int* in_sizes, int n_in,
                              void* d_out, int out_size, void* d_ws, size_t ws_size,
                              hipStream_t stream)
{
  const float* x = (const float*)d_in[0];  // [64][16384][8]
  const float* W = (const float*)d_in[1];  // [16384][10][8][16]
  float* out = (float*)d_out;              // [64][10][16]

  const size_t WB_SZ = (size_t)N_ * WNU_ * 4;            // 41.9 MB
  const size_t XC_SZ = (size_t)N_ * B_ * 4 * 4;          // 16.8 MB
  const size_t PARTS_SZ = (size_t)GRID_ * SVU_ * 4;      // 21.0 MB
  const size_t OUT32_SZ = (size_t)NJ_ * SVOL_ * 4;       // 1.3 MB
  const size_t VACC_SZ = (size_t)SVOL_ * 4;
  const int RB = NJ_ * (SVU_ / 256);                     // 640
  const int SB = SVOL_ / 256;                            // 40

  if (ws_size >= WB_SZ + XC_SZ + PARTS_SZ + OUT32_SZ + VACC_SZ) {
    // ---- tier A: fused convert in pass0, bf16 partials ----
    uint32_t* Wb = (uint32_t*)d_ws;
    uint32_t* xcv = (uint32_t*)((char*)d_ws + WB_SZ);
    uint32_t* parts = (uint32_t*)((char*)d_ws + WB_SZ + XC_SZ);
    float* out32 = (float*)((char*)d_ws + WB_SZ + XC_SZ + PARTS_SZ);
    float* vacc = out32 + (size_t)NJ_ * SVOL_;

    pass0_kernel<1, 1><<<GRID_, 256, 0, stream>>>(x, W, Wb, xcv, parts, nullptr, 0);
    reduce32_kernel<<<RB, 256, 0, stream>>>(parts, out32);
    squash_kernel<0><<<SB, 256, 0, stream>>>(out32, NJ_, vacc, out);

    accum_kernel<1, 1><<<GRID_, 256, 0, stream>>>(x, W, Wb, xcv, vacc, parts, nullptr, 0);
    reduce32_kernel<<<RB, 256, 0, stream>>>(parts, out32);
    squash_kernel<1><<<SB, 256, 0, stream>>>(out32, NJ_, vacc, out);

    accum_kernel<1, 1><<<GRID_, 256, 0, stream>>>(x, W, Wb, xcv, vacc, parts, nullptr, 0);
    reduce32_kernel<<<RB, 256, 0, stream>>>(parts, out32);
    squash_kernel<2><<<SB, 256, 0, stream>>>(out32, NJ_, vacc, out);
  } else if (ws_size >= PARTS_SZ + OUT32_SZ + VACC_SZ) {
    // ---- tier B: no room for Wb/xc; f32 staging each pass ----
    uint32_t* parts = (uint32_t*)d_ws;
    float* out32 = (float*)((char*)d_ws + PARTS_SZ);
    float* vacc = out32 + (size_t)NJ_ * SVOL_;

    pass0_kernel<0, 1><<<GRID_, 256, 0, stream>>>(x, W, nullptr, nullptr, parts, nullptr, 0);
    reduce32_kernel<<<RB, 256, 0, stream>>>(parts, out32);
    squash_kernel<0><<<SB, 256, 0, stream>>>(out32, NJ_, vacc, out);

    accum_kernel<0, 1><<<GRID_, 256, 0, stream>>>(x, W, nullptr, nullptr, vacc, parts, nullptr, 0);
    reduce32_kernel<<<RB, 256, 0, stream>>>(parts, out32);
    squash_kernel<1><<<SB, 256, 0, stream>>>(out32, NJ_, vacc, out);

    accum_kernel<0, 1><<<GRID_, 256, 0, stream>>>(x, W, nullptr, nullptr, vacc, parts, nullptr, 0);
    reduce32_kernel<<<RB, 256, 0, stream>>>(parts, out32);
    squash_kernel<2><<<SB, 256, 0, stream>>>(out32, NJ_, vacc, out);
  } else {
    // ---- tier C: atomic stripes (r7-verified) ----
    int ncopy = 64;
    while (ncopy > 1 && (size_t)(ncopy + 1) * SVOL_ * 4 > ws_size) ncopy >>= 1;
    float* s_ws = (float*)d_ws;
    float* vacc = s_ws + (size_t)ncopy * SVOL_;
    hipMemsetAsync(s_ws, 0, (size_t)ncopy * SVOL_ * 4, stream);

    pass0_kernel<0, 0><<<GRID_, 256, 0, stream>>>(x, W, nullptr, nullptr, nullptr, s_ws, ncopy);
    squash_stripes_kernel<0><<<SB, 256, 0, stream>>>(s_ws, ncopy, vacc, out);

    accum_kernel<0, 0><<<GRID_, 256, 0, stream>>>(x, W, nullptr, nullptr, vacc, nullptr, s_ws, ncopy);
    squash_stripes_kernel<1><<<SB, 256, 0, stream>>>(s_ws, ncopy, vacc, out);

    accum_kernel<0, 0><<<GRID_, 256, 0, stream>>>(x, W, nullptr, nullptr, vacc, nullptr, s_ws, ncopy);
    squash_stripes_kernel<2><<<SB, 256, 0, stream>>>(s_ws, ncopy, vacc, out);
  }
}